// Round 17
// baseline (132.818 us; speedup 1.0000x reference)
//
#include <hip/hip_runtime.h>
#include <hip/hip_bf16.h>

typedef __bf16 bf16_t;
typedef __attribute__((ext_vector_type(8))) __bf16 bf16x8;
typedef __attribute__((ext_vector_type(4))) float f32x4;
typedef __attribute__((ext_vector_type(2))) unsigned int u32x2;
typedef unsigned int u32;
typedef unsigned short u16;

// B=2, T=2048, D=1024, H=16, HD=64

__device__ __forceinline__ u32 pack2(float a, float b) {
    u16 ua = __builtin_bit_cast(u16, (bf16_t)a);
    u16 ub = __builtin_bit_cast(u16, (bf16_t)b);
    return (u32)ua | ((u32)ub << 16);
}

__device__ __forceinline__ bf16x8 cvt8(float4 f0, float4 f1) {
    bf16x8 v;
    v[0]=(bf16_t)f0.x; v[1]=(bf16_t)f0.y; v[2]=(bf16_t)f0.z; v[3]=(bf16_t)f0.w;
    v[4]=(bf16_t)f1.x; v[5]=(bf16_t)f1.y; v[6]=(bf16_t)f1.z; v[7]=(bf16_t)f1.w;
    return v;
}

__device__ __forceinline__ float exp2_fast(float x) {
    float r;
    asm("v_exp_f32 %0, %1" : "=v"(r) : "v"(x));
    return r;
}

__device__ __forceinline__ void gload_lds16(const void* g, void* l) {
    __builtin_amdgcn_global_load_lds(
        (const __attribute__((address_space(1))) unsigned int*)g,
        (__attribute__((address_space(3))) unsigned int*)l, 16, 0, 0);
}

// ---------------- Kernel 0: prep (convert + transpose weights) ----------------
__global__ __launch_bounds__(256) void prep_kernel(
    const float* __restrict__ x,
    const float* __restrict__ kv_w,
    const float* __restrict__ out_w,
    bf16_t* __restrict__ xb,
    bf16_t* __restrict__ kv_wt,
    bf16_t* __restrict__ out_wt)
{
    __shared__ bf16_t T[64 * 72];
    const int blk = blockIdx.x;
    const int tid = threadIdx.x;

    if (blk < 1024) {
        const size_t base = (size_t)blk * 4096 + tid * 16;
        const float4* p = (const float4*)(x + base);
        float4 f0 = p[0], f1 = p[1], f2 = p[2], f3 = p[3];
        *(bf16x8*)(xb + base)     = cvt8(f0, f1);
        *(bf16x8*)(xb + base + 8) = cvt8(f2, f3);
        return;
    }

    const bool is_kv = (blk < 1536);
    const int t = is_kv ? (blk - 1024) : (blk - 1536);
    const int k0 = is_kv ? (t >> 5) * 64 : (t >> 4) * 64;
    const int n0 = is_kv ? (t & 31) * 64 : (t & 15) * 64;
    const int srcld = is_kv ? 2048 : 1024;
    const float* W = is_kv ? kv_w : out_w;
    bf16_t* Wt = is_kv ? kv_wt : out_wt;

    {
        const int r = tid >> 2, c4 = (tid & 3) * 16;
        const float4* p = (const float4*)(W + (size_t)(k0 + r) * srcld + n0 + c4);
        float4 f0 = p[0], f1 = p[1], f2 = p[2], f3 = p[3];
        *(bf16x8*)&T[r * 72 + c4]     = cvt8(f0, f1);
        *(bf16x8*)&T[r * 72 + c4 + 8] = cvt8(f2, f3);
    }
    __syncthreads();
    {
        const int n = tid >> 2, kc = (tid & 3) * 16;
        bf16x8 o0, o1;
#pragma unroll
        for (int kk = 0; kk < 8; kk++) o0[kk] = T[(kc + kk) * 72 + n];
#pragma unroll
        for (int kk = 0; kk < 8; kk++) o1[kk] = T[(kc + 8 + kk) * 72 + n];
        *(bf16x8*)(Wt + (size_t)(n0 + n) * 1024 + k0 + kc)     = o0;
        *(bf16x8*)(Wt + (size_t)(n0 + n) * 1024 + k0 + kc + 8) = o1;
    }
}

// ---------------- Kernel 1: KV projection GEMM (BK=64, swizzled LDS) ----------------
__global__ __launch_bounds__(256, 2) void kv_gemm_kernel(
    const bf16_t* __restrict__ xb,
    const bf16_t* __restrict__ wt,      // [2048][1024]
    const float* __restrict__ kv_b,
    bf16_t* __restrict__ Kbuf,
    bf16_t* __restrict__ Vt)
{
    __shared__ bf16_t L[2][2][128 * 64];   // [buf][A/B][row][64], 64 KB

    const int tid = threadIdx.x;
    const int w = tid >> 6, ln = tid & 63;
    const int g = ln >> 4, qc = ln & 15;
    const int braw = blockIdx.x;
    const int bsw = (braw & 7) * 64 + (braw >> 3);   // 512 blocks
    const int n0 = (bsw & 15) * 128, m0 = (bsw >> 4) * 128;
    const int wm = (w >> 1) * 64, wn = (w & 1) * 64;
    const int srow = ln >> 3, sslot = ln & 7;
    const int scol = (sslot ^ srow) * 8;             // inverse-swizzled source chunk

    f32x4 acc[4][4];
    const f32x4 z = {0.f, 0.f, 0.f, 0.f};
#pragma unroll
    for (int i = 0; i < 4; i++)
#pragma unroll
        for (int j = 0; j < 4; j++) acc[i][j] = z;

    const bf16_t* Abase = xb + (size_t)(m0 + w * 32 + srow) * 1024 + scol;
    const bf16_t* Bbase = wt + (size_t)(n0 + w * 32 + srow) * 1024 + scol;

#define KV_STAGE(buf, k0)                                                        \
    {                                                                            \
        _Pragma("unroll")                                                        \
        for (int i = 0; i < 4; i++) {                                            \
            gload_lds16(Abase + (size_t)i * 8 * 1024 + (k0), &L[buf][0][(w * 32 + i * 8) * 64]); \
            gload_lds16(Bbase + (size_t)i * 8 * 1024 + (k0), &L[buf][1][(w * 32 + i * 8) * 64]); \
        }                                                                        \
    }

    KV_STAGE(0, 0);
    __syncthreads();

    int cur = 0;
    const int swz = qc & 7;
    for (int ks = 0; ks < 16; ks++) {
        if (ks < 15) KV_STAGE(cur ^ 1, (ks + 1) * 64);
        bf16x8 af[2][4], bfv[2][4];
#pragma unroll
        for (int kk = 0; kk < 2; kk++) {
#pragma unroll
            for (int i = 0; i < 4; i++)
                af[kk][i]  = *(const bf16x8*)&L[cur][0][(wm + i * 16 + qc) * 64 + (((kk * 4 + g) ^ swz) * 8)];
#pragma unroll
            for (int j = 0; j < 4; j++)
                bfv[kk][j] = *(const bf16x8*)&L[cur][1][(wn + j * 16 + qc) * 64 + (((kk * 4 + g) ^ swz) * 8)];
        }
#pragma unroll
        for (int kk = 0; kk < 2; kk++)
#pragma unroll
            for (int i = 0; i < 4; i++)
#pragma unroll
                for (int j = 0; j < 4; j++)
                    acc[i][j] = __builtin_amdgcn_mfma_f32_16x16x32_bf16(af[kk][i], bfv[kk][j], acc[i][j], 0, 0, 0);
        __syncthreads();
        cur ^= 1;
    }
#undef KV_STAGE

    if (n0 < 1024) {
        // K half: d-contiguous stores
#pragma unroll
        for (int i = 0; i < 4; i++) {
#pragma unroll
            for (int j = 0; j < 4; j++) {
                const int colg = n0 + wn + j * 16 + qc;
                const float bias = kv_b[colg];
                const int h = colg >> 6, d = colg & 63;
#pragma unroll
                for (int r = 0; r < 4; r++) {
                    const int rowg = m0 + wm + i * 16 + g * 4 + r;
                    const int b = rowg >> 11, t = rowg & 2047;
                    Kbuf[(((size_t)(b * 16 + h) * 2048 + t) << 6) + d] = (bf16_t)(acc[i][j][r] + bias);
                }
            }
        }
    } else {
        // V half: transpose via LDS (pad 134), then coalesced 16B stores
        bf16_t* T = (bf16_t*)L;
#pragma unroll
        for (int i = 0; i < 4; i++) {
#pragma unroll
            for (int j = 0; j < 4; j++) {
                const int nloc = wn + j * 16 + qc;
                const float bias = kv_b[n0 + nloc];
                const int mloc = wm + i * 16 + g * 4;
                *(u32*)&T[nloc * 134 + mloc]     = pack2(acc[i][j][0] + bias, acc[i][j][1] + bias);
                *(u32*)&T[nloc * 134 + mloc + 2] = pack2(acc[i][j][2] + bias, acc[i][j][3] + bias);
            }
        }
        __syncthreads();
        const int n = tid >> 1, mh = (tid & 1) * 64;
        const int d = n0 - 1024 + n;
        const int b = m0 >> 11;
        const int t0 = (m0 & 2047) + mh;
        bf16_t* dst = Vt + (((size_t)(b * 16 + (d >> 6)) * 64 + (d & 63)) << 11) + t0;
#pragma unroll
        for (int k = 0; k < 8; k++)
            *(bf16x8*)(dst + k * 8) = *(const bf16x8*)&T[n * 134 + mh + k * 8];
    }
}

// ---------------- Kernel 2: fused attention (r10 structure, confirmed fix) ----------------
// 4 waves x 16 q-rows, 1024 blocks x 64 q-rows (qt loop dropped). Formulas
// are the symbol-audited r10 set; difference from failing r10 is ONLY the
// removal of __launch_bounds__(256,3) (round-14 A/B confirmed min-waves>=3 +
// global_load_lds dbuf => corruption) plus the TBAA fence.
// LDS 41984 B -> 3 blocks/CU x 4 waves = 12 waves/CU with the 1024 grid.
__global__ __launch_bounds__(256) void attn_kernel(
    const float* __restrict__ q,
    const bf16_t* __restrict__ Kbuf,
    const bf16_t* __restrict__ Vt,
    bf16_t* __restrict__ attn)
{
    __shared__ bf16_t Klds[2][64 * 64];
    __shared__ bf16_t Vlds[2][64 * 64];
    __shared__ bf16_t Plds[4][16 * 72];

    const int tid = threadIdx.x;
    const int wv = tid >> 6;          // 0..3
    const int ln = tid & 63;
    const int g = ln >> 4, qc = ln & 15;
    const int q7 = qc & 7;

    // 1024 blocks; XCD c covers bh in [c*4, c*4+4) (2 MB K/V < 4 MB L2)
    const int braw = blockIdx.x;
    const int bsw = (braw & 7) * 128 + (braw >> 3);
    const int bh = bsw >> 5;          // 0..31
    const int qb = bsw & 31;          // 0..31
    const int b = bh >> 4, h = bh & 15;
    const int q0 = qb * 64 + wv * 16;

    const float qscale = 0.125f * 1.44269504088896f;
    bf16x8 qf[2];
    {
        const float* qp = q + ((size_t)(b * 2048 + q0 + qc) * 1024) + h * 64 + g * 8;
#pragma unroll
        for (int c = 0; c < 2; c++) {
            float4 f0 = *(const float4*)(qp + c * 32);
            float4 f1 = *(const float4*)(qp + c * 32 + 4);
            f0.x*=qscale; f0.y*=qscale; f0.z*=qscale; f0.w*=qscale;
            f1.x*=qscale; f1.y*=qscale; f1.z*=qscale; f1.w*=qscale;
            qf[c] = cvt8(f0, f1);
        }
    }

    const bf16_t* Kb = Kbuf + (size_t)bh * (2048 * 64);
    const bf16_t* Vb = Vt + (size_t)bh * (64 * 2048);

    float l_part = 0.0f;
    f32x4 acc[4];
    const f32x4 z = {0.f, 0.f, 0.f, 0.f};
#pragma unroll
    for (int dt = 0; dt < 4; dt++) acc[dt] = z;

    // staging: VERBATIM round-6/11 formulas (wave wv stages rows wv*16..wv*16+15)
    const int srow = ln >> 3;
    const int sc16 = ln & 7;

#pragma unroll
    for (int i = 0; i < 2; i++) {
        const int row = wv * 16 + i * 8 + srow;
        const int slot = sc16 ^ (row & 7);
        gload_lds16(Kb + (size_t)row * 64 + slot * 8,       &Klds[0][(wv * 16 + i * 8) * 64]);
        gload_lds16(Vb + (size_t)row * 2048 + 0 + slot * 8, &Vlds[0][(wv * 16 + i * 8) * 64]);
    }
    __syncthreads();

    int cur = 0;
    for (int t = 0; t < 32; ++t) {
        const int kv0 = t * 64;
        if (t + 1 < 32) {
            const int kvn = kv0 + 64;
#pragma unroll
            for (int i = 0; i < 2; i++) {
                const int row = wv * 16 + i * 8 + srow;
                const int slot = sc16 ^ (row & 7);
                gload_lds16(Kb + (size_t)(kvn + row) * 64 + slot * 8, &Klds[cur ^ 1][(wv * 16 + i * 8) * 64]);
                gload_lds16(Vb + (size_t)row * 2048 + kvn + slot * 8, &Vlds[cur ^ 1][(wv * 16 + i * 8) * 64]);
            }
        }

        const bf16_t* Kl = Klds[cur];
        const bf16_t* Vl = Vlds[cur];

        // ---- S^T = K · Q^T  (lane: q=qc, kv = kt*16 + g*4 + r)
        f32x4 st[4];
#pragma unroll
        for (int kt = 0; kt < 4; kt++) {
            bf16x8 k0 = *(const bf16x8*)&Kl[(kt * 16 + qc) * 64 + ((g       ^ q7) * 8)];
            bf16x8 k1 = *(const bf16x8*)&Kl[(kt * 16 + qc) * 64 + (((4 + g) ^ q7) * 8)];
            f32x4 s = __builtin_amdgcn_mfma_f32_16x16x32_bf16(k0, qf[0], z, 0, 0, 0);
            st[kt] = __builtin_amdgcn_mfma_f32_16x16x32_bf16(k1, qf[1], s, 0, 0, 0);
        }

        // ---- V fragments (round-6 pattern)
        bf16x8 vf[4][2];
#pragma unroll
        for (int dt = 0; dt < 4; dt++)
#pragma unroll
            for (int ks = 0; ks < 2; ks++)
                vf[dt][ks] = *(const bf16x8*)&Vl[(dt * 16 + qc) * 64 + (((ks * 4 + g) ^ q7) * 8)];

        // ---- unnormalized softmax: p = exp2(s)
        float p[16];
        float s0 = 0.f, s1 = 0.f;
#pragma unroll
        for (int kt = 0; kt < 4; kt++)
#pragma unroll
            for (int r = 0; r < 4; r++) {
                float pv = exp2_fast(st[kt][r]);
                p[kt * 4 + r] = pv;
                if (r & 1) s1 += pv; else s0 += pv;
            }
        l_part += s0 + s1;

        // ---- P -> LDS (stride-72 layout)
        bf16_t* Pq = &Plds[wv][0];
#pragma unroll
        for (int kt = 0; kt < 4; kt++) {
            u32x2 wpk;
            wpk[0] = pack2(p[kt * 4 + 0], p[kt * 4 + 1]);
            wpk[1] = pack2(p[kt * 4 + 2], p[kt * 4 + 3]);
            *(u32x2*)&Pq[qc * 72 + kt * 16 + g * 4] = wpk;
        }
        asm volatile("" ::: "memory");   // order P writes before P reads (TBAA)
        bf16x8 pf0 = *(const bf16x8*)&Pq[qc * 72 + g * 8];
        bf16x8 pf1 = *(const bf16x8*)&Pq[qc * 72 + 32 + g * 8];

        // ---- P·V
#pragma unroll
        for (int dt = 0; dt < 4; dt++) {
            acc[dt] = __builtin_amdgcn_mfma_f32_16x16x32_bf16(pf0, vf[dt][0], acc[dt], 0, 0, 0);
            acc[dt] = __builtin_amdgcn_mfma_f32_16x16x32_bf16(pf1, vf[dt][1], acc[dt], 0, 0, 0);
        }

        __syncthreads();
        cur ^= 1;
    }

    // ---- normalize & store
    {
        float lsum = l_part;
        lsum += __shfl_xor(lsum, 16);
        lsum += __shfl_xor(lsum, 32);
        float li[4];
#pragma unroll
        for (int r = 0; r < 4; r++) li[r] = 1.0f / __shfl(lsum, g * 4 + r);
#pragma unroll
        for (int dt = 0; dt < 4; dt++)
#pragma unroll
            for (int r = 0; r < 4; r++) {
                const float o = acc[dt][r] * li[r];
                const int trow = q0 + g * 4 + r;
                attn[((size_t)(b * 2048 + trow)) * 1024 + h * 64 + dt * 16 + qc] = (bf16_t)o;
            }
    }
}

// ---------------- Kernel 3: output projection GEMM (BK=64, swizzled LDS) ----------------
__global__ __launch_bounds__(256, 2) void out_gemm_kernel(
    const bf16_t* __restrict__ attn,
    const bf16_t* __restrict__ wt,      // out_w^T bf16 [1024][1024]
    const float* __restrict__ out_b,
    float* __restrict__ out)
{
    __shared__ bf16_t L[2][2][128 * 64];

    const int tid = threadIdx.x;
    const int w = tid >> 6, ln = tid & 63;
    const int g = ln >> 4, qc = ln & 15;
    const int braw = blockIdx.x;
    const int bsw = (braw & 7) * 32 + (braw >> 3);   // 256 blocks
    const int n0 = (bsw & 7) * 128, m0 = (bsw >> 3) * 128;
    const int wm = (w >> 1) * 64, wn = (w & 1) * 64;
    const int srow = ln >> 3, sslot = ln & 7;
    const int scol = (sslot ^ srow) * 8;

    f32x4 acc[4][4];
    const f32x4 z = {0.f, 0.f, 0.f, 0.f};
#pragma unroll
    for (int i = 0; i < 4; i++)
#pragma unroll
        for (int j = 0; j < 4; j++) acc[i][j] = z;

    const bf16_t* Abase = attn + (size_t)(m0 + w * 32 + srow) * 1024 + scol;
    const bf16_t* Bbase = wt   + (size_t)(n0 + w * 32 + srow) * 1024 + scol;

#define OG_STAGE(buf, k0)                                                        \
    {                                                                            \
        _Pragma("unroll")                                                        \
        for (int i = 0; i < 4; i++) {                                            \
            gload_lds16(Abase + (size_t)i * 8 * 1024 + (k0), &L[buf][0][(w * 32 + i * 8) * 64]); \
            gload_lds16(Bbase + (size_t)i * 8 * 1024 + (k0), &L[buf][1][(w * 32 + i * 8) * 64]); \
        }                                                                        \
    }

    OG_STAGE(0, 0);
    __syncthreads();

    int cur = 0;
    const int swz = qc & 7;
    for (int ks = 0; ks < 16; ks++) {
        if (ks < 15) OG_STAGE(cur ^ 1, (ks + 1) * 64);
        bf16x8 af[2][4], bfv[2][4];
#pragma unroll
        for (int kk = 0; kk < 2; kk++) {
#pragma unroll
            for (int i = 0; i < 4; i++)
                af[kk][i]  = *(const bf16x8*)&L[cur][0][(wm + i * 16 + qc) * 64 + (((kk * 4 + g) ^ swz) * 8)];
#pragma unroll
            for (int j = 0; j < 4; j++)
                bfv[kk][j] = *(const bf16x8*)&L[cur][1][(wn + j * 16 + qc) * 64 + (((kk * 4 + g) ^ swz) * 8)];
        }
#pragma unroll
        for (int kk = 0; kk < 2; kk++)
#pragma unroll
            for (int i = 0; i < 4; i++)
#pragma unroll
                for (int j = 0; j < 4; j++)
                    acc[i][j] = __builtin_amdgcn_mfma_f32_16x16x32_bf16(af[kk][i], bfv[kk][j], acc[i][j], 0, 0, 0);
        __syncthreads();
        cur ^= 1;
    }
#undef OG_STAGE

#pragma unroll
    for (int i = 0; i < 4; i++) {
#pragma unroll
        for (int j = 0; j < 4; j++) {
            const int colg = n0 + wn + j * 16 + qc;
            const float bias = out_b[colg];
#pragma unroll
            for (int r = 0; r < 4; r++) {
                const int rowg = m0 + wm + i * 16 + g * 4 + r;
                out[(size_t)rowg * 1024 + colg] = acc[i][j][r] + bias;
            }
        }
    }
}

extern "C" void kernel_launch(void* const* d_in, const int* in_sizes, int n_in,
                              void* d_out, int out_size, void* d_ws, size_t ws_size,
                              hipStream_t stream) {
    const float* x     = (const float*)d_in[0];
    const float* q     = (const float*)d_in[1];
    const float* kv_w  = (const float*)d_in[2];
    const float* kv_b  = (const float*)d_in[3];
    const float* out_w = (const float*)d_in[4];
    const float* out_b = (const float*)d_in[5];
    float* out = (float*)d_out;

    bf16_t* xb     = (bf16_t*)d_ws;
    bf16_t* kv_wt  = xb + (size_t)4096 * 1024;
    bf16_t* out_wt = kv_wt + (size_t)2048 * 1024;
    bf16_t* Kbuf   = out_wt + (size_t)1024 * 1024;
    bf16_t* Vt     = Kbuf + (size_t)32 * 2048 * 64;
    bf16_t* attnb  = Vt + (size_t)32 * 2048 * 64;

    prep_kernel<<<dim3(1792), 256, 0, stream>>>(x, kv_w, out_w, xb, kv_wt, out_wt);
    kv_gemm_kernel<<<dim3(512), 256, 0, stream>>>(xb, kv_wt, kv_b, Kbuf, Vt);
    attn_kernel<<<dim3(1024), 256, 0, stream>>>(q, Kbuf, Vt, attnb);
    out_gemm_kernel<<<dim3(256), 256, 0, stream>>>(attnb, out_wt, out_b, out);
}

// Round 18
// 113.927 us; speedup vs baseline: 1.1658x; 1.1658x over previous
//
#include <hip/hip_runtime.h>
#include <hip/hip_bf16.h>

typedef __bf16 bf16_t;
typedef __attribute__((ext_vector_type(8))) __bf16 bf16x8;
typedef __attribute__((ext_vector_type(4))) float f32x4;
typedef __attribute__((ext_vector_type(2))) unsigned int u32x2;
typedef unsigned int u32;
typedef unsigned short u16;

// B=2, T=2048, D=1024, H=16, HD=64

__device__ __forceinline__ u32 pack2(float a, float b) {
    u16 ua = __builtin_bit_cast(u16, (bf16_t)a);
    u16 ub = __builtin_bit_cast(u16, (bf16_t)b);
    return (u32)ua | ((u32)ub << 16);
}

__device__ __forceinline__ bf16x8 cvt8(float4 f0, float4 f1) {
    bf16x8 v;
    v[0]=(bf16_t)f0.x; v[1]=(bf16_t)f0.y; v[2]=(bf16_t)f0.z; v[3]=(bf16_t)f0.w;
    v[4]=(bf16_t)f1.x; v[5]=(bf16_t)f1.y; v[6]=(bf16_t)f1.z; v[7]=(bf16_t)f1.w;
    return v;
}

__device__ __forceinline__ float exp2_fast(float x) {
    float r;
    asm("v_exp_f32 %0, %1" : "=v"(r) : "v"(x));
    return r;
}

__device__ __forceinline__ void gload_lds16(const void* g, void* l) {
    __builtin_amdgcn_global_load_lds(
        (const __attribute__((address_space(1))) unsigned int*)g,
        (__attribute__((address_space(3))) unsigned int*)l, 16, 0, 0);
}

// ---------------- Kernel 0: prep (convert + transpose weights) ----------------
__global__ __launch_bounds__(256) void prep_kernel(
    const float* __restrict__ x,
    const float* __restrict__ kv_w,
    const float* __restrict__ out_w,
    bf16_t* __restrict__ xb,
    bf16_t* __restrict__ kv_wt,
    bf16_t* __restrict__ out_wt)
{
    __shared__ bf16_t T[64 * 72];
    const int blk = blockIdx.x;
    const int tid = threadIdx.x;

    if (blk < 1024) {
        const size_t base = (size_t)blk * 4096 + tid * 16;
        const float4* p = (const float4*)(x + base);
        float4 f0 = p[0], f1 = p[1], f2 = p[2], f3 = p[3];
        *(bf16x8*)(xb + base)     = cvt8(f0, f1);
        *(bf16x8*)(xb + base + 8) = cvt8(f2, f3);
        return;
    }

    const bool is_kv = (blk < 1536);
    const int t = is_kv ? (blk - 1024) : (blk - 1536);
    const int k0 = is_kv ? (t >> 5) * 64 : (t >> 4) * 64;
    const int n0 = is_kv ? (t & 31) * 64 : (t & 15) * 64;
    const int srcld = is_kv ? 2048 : 1024;
    const float* W = is_kv ? kv_w : out_w;
    bf16_t* Wt = is_kv ? kv_wt : out_wt;

    {
        const int r = tid >> 2, c4 = (tid & 3) * 16;
        const float4* p = (const float4*)(W + (size_t)(k0 + r) * srcld + n0 + c4);
        float4 f0 = p[0], f1 = p[1], f2 = p[2], f3 = p[3];
        *(bf16x8*)&T[r * 72 + c4]     = cvt8(f0, f1);
        *(bf16x8*)&T[r * 72 + c4 + 8] = cvt8(f2, f3);
    }
    __syncthreads();
    {
        const int n = tid >> 2, kc = (tid & 3) * 16;
        bf16x8 o0, o1;
#pragma unroll
        for (int kk = 0; kk < 8; kk++) o0[kk] = T[(kc + kk) * 72 + n];
#pragma unroll
        for (int kk = 0; kk < 8; kk++) o1[kk] = T[(kc + 8 + kk) * 72 + n];
        *(bf16x8*)(Wt + (size_t)(n0 + n) * 1024 + k0 + kc)     = o0;
        *(bf16x8*)(Wt + (size_t)(n0 + n) * 1024 + k0 + kc + 8) = o1;
    }
}

// ---------------- Kernel 1: KV projection GEMM (BK=64, swizzled LDS) ----------------
__global__ __launch_bounds__(256, 2) void kv_gemm_kernel(
    const bf16_t* __restrict__ xb,
    const bf16_t* __restrict__ wt,      // [2048][1024]
    const float* __restrict__ kv_b,
    bf16_t* __restrict__ Kbuf,
    bf16_t* __restrict__ Vt)
{
    __shared__ bf16_t L[2][2][128 * 64];   // [buf][A/B][row][64], 64 KB

    const int tid = threadIdx.x;
    const int w = tid >> 6, ln = tid & 63;
    const int g = ln >> 4, qc = ln & 15;
    const int braw = blockIdx.x;
    const int bsw = (braw & 7) * 64 + (braw >> 3);   // 512 blocks
    const int n0 = (bsw & 15) * 128, m0 = (bsw >> 4) * 128;
    const int wm = (w >> 1) * 64, wn = (w & 1) * 64;
    const int srow = ln >> 3, sslot = ln & 7;
    const int scol = (sslot ^ srow) * 8;             // inverse-swizzled source chunk

    f32x4 acc[4][4];
    const f32x4 z = {0.f, 0.f, 0.f, 0.f};
#pragma unroll
    for (int i = 0; i < 4; i++)
#pragma unroll
        for (int j = 0; j < 4; j++) acc[i][j] = z;

    const bf16_t* Abase = xb + (size_t)(m0 + w * 32 + srow) * 1024 + scol;
    const bf16_t* Bbase = wt + (size_t)(n0 + w * 32 + srow) * 1024 + scol;

#define KV_STAGE(buf, k0)                                                        \
    {                                                                            \
        _Pragma("unroll")                                                        \
        for (int i = 0; i < 4; i++) {                                            \
            gload_lds16(Abase + (size_t)i * 8 * 1024 + (k0), &L[buf][0][(w * 32 + i * 8) * 64]); \
            gload_lds16(Bbase + (size_t)i * 8 * 1024 + (k0), &L[buf][1][(w * 32 + i * 8) * 64]); \
        }                                                                        \
    }

    KV_STAGE(0, 0);
    __syncthreads();

    int cur = 0;
    const int swz = qc & 7;
    for (int ks = 0; ks < 16; ks++) {
        if (ks < 15) KV_STAGE(cur ^ 1, (ks + 1) * 64);
        bf16x8 af[2][4], bfv[2][4];
#pragma unroll
        for (int kk = 0; kk < 2; kk++) {
#pragma unroll
            for (int i = 0; i < 4; i++)
                af[kk][i]  = *(const bf16x8*)&L[cur][0][(wm + i * 16 + qc) * 64 + (((kk * 4 + g) ^ swz) * 8)];
#pragma unroll
            for (int j = 0; j < 4; j++)
                bfv[kk][j] = *(const bf16x8*)&L[cur][1][(wn + j * 16 + qc) * 64 + (((kk * 4 + g) ^ swz) * 8)];
        }
#pragma unroll
        for (int kk = 0; kk < 2; kk++)
#pragma unroll
            for (int i = 0; i < 4; i++)
#pragma unroll
                for (int j = 0; j < 4; j++)
                    acc[i][j] = __builtin_amdgcn_mfma_f32_16x16x32_bf16(af[kk][i], bfv[kk][j], acc[i][j], 0, 0, 0);
        __syncthreads();
        cur ^= 1;
    }
#undef KV_STAGE

    if (n0 < 1024) {
        // K half: d-contiguous stores
#pragma unroll
        for (int i = 0; i < 4; i++) {
#pragma unroll
            for (int j = 0; j < 4; j++) {
                const int colg = n0 + wn + j * 16 + qc;
                const float bias = kv_b[colg];
                const int h = colg >> 6, d = colg & 63;
#pragma unroll
                for (int r = 0; r < 4; r++) {
                    const int rowg = m0 + wm + i * 16 + g * 4 + r;
                    const int b = rowg >> 11, t = rowg & 2047;
                    Kbuf[(((size_t)(b * 16 + h) * 2048 + t) << 6) + d] = (bf16_t)(acc[i][j][r] + bias);
                }
            }
        }
    } else {
        // V half: transpose via LDS (pad 134), then coalesced 16B stores
        bf16_t* T = (bf16_t*)L;
#pragma unroll
        for (int i = 0; i < 4; i++) {
#pragma unroll
            for (int j = 0; j < 4; j++) {
                const int nloc = wn + j * 16 + qc;
                const float bias = kv_b[n0 + nloc];
                const int mloc = wm + i * 16 + g * 4;
                *(u32*)&T[nloc * 134 + mloc]     = pack2(acc[i][j][0] + bias, acc[i][j][1] + bias);
                *(u32*)&T[nloc * 134 + mloc + 2] = pack2(acc[i][j][2] + bias, acc[i][j][3] + bias);
            }
        }
        __syncthreads();
        const int n = tid >> 1, mh = (tid & 1) * 64;
        const int d = n0 - 1024 + n;
        const int b = m0 >> 11;
        const int t0 = (m0 & 2047) + mh;
        bf16_t* dst = Vt + (((size_t)(b * 16 + (d >> 6)) * 64 + (d & 63)) << 11) + t0;
#pragma unroll
        for (int k = 0; k < 8; k++)
            *(bf16x8*)(dst + k * 8) = *(const bf16x8*)&T[n * 134 + mh + k * 8];
    }
}

// ---------------- Kernel 2: fused attention, split-KV + per-qt P buffer ----------------
// r12's split-KV kernel (passed) with r16's qt-interleaved single P buffer
// (passed): Plds halves to [4][16*72] -> LDS 41984 B -> 3 blocks/CU with the
// 1024-block grid (12 waves/CU). All formulas verbatim from those two kernels.
__global__ __launch_bounds__(256) void attn_kernel(
    const float* __restrict__ q,
    const bf16_t* __restrict__ Kbuf,
    const bf16_t* __restrict__ Vt,
    bf16_t* __restrict__ part0,
    bf16_t* __restrict__ part1,
    float* __restrict__ lbuf)
{
    __shared__ bf16_t Klds[2][64 * 64];
    __shared__ bf16_t Vlds[2][64 * 64];
    __shared__ bf16_t Plds[4][16 * 72];

    const int tid = threadIdx.x;
    const int wv = tid >> 6;
    const int ln = tid & 63;
    const int g = ln >> 4, qc = ln & 15;

    // 1024 blocks; XCD c covers 4 bh values (2 MB K/V < 4 MB L2)
    const int braw = blockIdx.x;
    const int bsw = (braw & 7) * 128 + (braw >> 3);
    const int bh = bsw >> 5;              // 0..31
    const int qb = (bsw >> 1) & 15;       // 0..15
    const int s  = bsw & 1;               // kv split
    const int b = bh >> 4, h = bh & 15;
    const int q0 = qb * 128 + wv * 32;

    const float qscale = 0.125f * 1.44269504088896f;
    bf16x8 qf[2][2];
#pragma unroll
    for (int qt = 0; qt < 2; qt++) {
        const float* qp = q + ((size_t)(b * 2048 + q0 + qt * 16 + qc) * 1024) + h * 64 + g * 8;
#pragma unroll
        for (int c = 0; c < 2; c++) {
            float4 f0 = *(const float4*)(qp + c * 32);
            float4 f1 = *(const float4*)(qp + c * 32 + 4);
            f0.x*=qscale; f0.y*=qscale; f0.z*=qscale; f0.w*=qscale;
            f1.x*=qscale; f1.y*=qscale; f1.z*=qscale; f1.w*=qscale;
            qf[qt][c] = cvt8(f0, f1);
        }
    }

    const bf16_t* Kb = Kbuf + (size_t)bh * (2048 * 64) + (size_t)s * (1024 * 64);
    const bf16_t* Vb = Vt + (size_t)bh * (64 * 2048) + s * 1024;

    float l_part[2] = {0.0f, 0.0f};
    f32x4 acc[2][4];
    const f32x4 z = {0.f, 0.f, 0.f, 0.f};
#pragma unroll
    for (int qt = 0; qt < 2; qt++)
#pragma unroll
        for (int dt = 0; dt < 4; dt++) acc[qt][dt] = z;

    const int srow = ln >> 3;
    const int sc16 = ln & 7;

#pragma unroll
    for (int i = 0; i < 2; i++) {
        const int row = wv * 16 + i * 8 + srow;
        const int slot = sc16 ^ (row & 7);
        gload_lds16(Kb + (size_t)row * 64 + slot * 8,       &Klds[0][(wv * 16 + i * 8) * 64]);
        gload_lds16(Vb + (size_t)row * 2048 + 0 + slot * 8, &Vlds[0][(wv * 16 + i * 8) * 64]);
    }
    __syncthreads();

    int cur = 0;
    for (int t = 0; t < 16; ++t) {
        const int kv0 = t * 64;
        if (t + 1 < 16) {
            const int kvn = kv0 + 64;
#pragma unroll
            for (int i = 0; i < 2; i++) {
                const int row = wv * 16 + i * 8 + srow;
                const int slot = sc16 ^ (row & 7);
                gload_lds16(Kb + (size_t)(kvn + row) * 64 + slot * 8, &Klds[cur ^ 1][(wv * 16 + i * 8) * 64]);
                gload_lds16(Vb + (size_t)row * 2048 + kvn + slot * 8, &Vlds[cur ^ 1][(wv * 16 + i * 8) * 64]);
            }
        }

        const bf16_t* Kl = Klds[cur];
        const bf16_t* Vl = Vlds[cur];

        // ---- S^T = K · Q^T  (already in exp2 domain)
        f32x4 st[4][2];
#pragma unroll
        for (int kt = 0; kt < 4; kt++) {
            bf16x8 k0 = *(const bf16x8*)&Kl[(kt * 16 + qc) * 64 + ((g       ^ (qc & 7)) * 8)];
            bf16x8 k1 = *(const bf16x8*)&Kl[(kt * 16 + qc) * 64 + (((4 + g) ^ (qc & 7)) * 8)];
#pragma unroll
            for (int qt = 0; qt < 2; qt++) {
                f32x4 sacc = __builtin_amdgcn_mfma_f32_16x16x32_bf16(k0, qf[qt][0], z, 0, 0, 0);
                st[kt][qt] = __builtin_amdgcn_mfma_f32_16x16x32_bf16(k1, qf[qt][1], sacc, 0, 0, 0);
            }
        }

        bf16x8 vf[4][2];
#pragma unroll
        for (int dt = 0; dt < 4; dt++)
#pragma unroll
            for (int ks = 0; ks < 2; ks++)
                vf[dt][ks] = *(const bf16x8*)&Vl[(dt * 16 + qc) * 64 + (((ks * 4 + g) ^ (qc & 7)) * 8)];

        // ---- per qt: unnormalized softmax -> P -> PV (single P buffer per wave)
        bf16_t* Pq = &Plds[wv][0];
#pragma unroll
        for (int qt = 0; qt < 2; qt++) {
            float p[16];
            float s0 = 0.f, s1 = 0.f;
#pragma unroll
            for (int kt = 0; kt < 4; kt++)
#pragma unroll
                for (int r = 0; r < 4; r++) {
                    float pv = exp2_fast(st[kt][qt][r]);
                    p[kt * 4 + r] = pv;
                    if (r & 1) s1 += pv; else s0 += pv;
                }
            l_part[qt] += s0 + s1;

#pragma unroll
            for (int kt = 0; kt < 4; kt++) {
                u32x2 wpk;
                wpk[0] = pack2(p[kt * 4 + 0], p[kt * 4 + 1]);
                wpk[1] = pack2(p[kt * 4 + 2], p[kt * 4 + 3]);
                *(u32x2*)&Pq[qc * 72 + kt * 16 + g * 4] = wpk;
            }
            asm volatile("" ::: "memory");   // order P writes before P reads (TBAA)
            bf16x8 pf0 = *(const bf16x8*)&Pq[qc * 72 + g * 8];
            bf16x8 pf1 = *(const bf16x8*)&Pq[qc * 72 + 32 + g * 8];
#pragma unroll
            for (int dt = 0; dt < 4; dt++) {
                acc[qt][dt] = __builtin_amdgcn_mfma_f32_16x16x32_bf16(pf0, vf[dt][0], acc[qt][dt], 0, 0, 0);
                acc[qt][dt] = __builtin_amdgcn_mfma_f32_16x16x32_bf16(pf1, vf[dt][1], acc[qt][dt], 0, 0, 0);
            }
            asm volatile("" ::: "memory");   // order P reads before next qt's writes
        }

        __syncthreads();
        cur ^= 1;
    }

    // ---- store partials (unnormalized O + l), r12 verbatim
    bf16_t* Obuf = s ? part1 : part0;
    float* lp = lbuf + (size_t)s * (32 * 2048);
#pragma unroll
    for (int qt = 0; qt < 2; qt++) {
        float lsum = l_part[qt];
        lsum += __shfl_xor(lsum, 16);
        lsum += __shfl_xor(lsum, 32);
        if (g == 0)
            lp[(b * 16 + h) * 2048 + q0 + qt * 16 + qc] = lsum;
#pragma unroll
        for (int dt = 0; dt < 4; dt++)
#pragma unroll
            for (int r = 0; r < 4; r++) {
                const int trow = q0 + qt * 16 + g * 4 + r;
                Obuf[((size_t)(b * 2048 + trow)) * 1024 + h * 64 + dt * 16 + qc] = (bf16_t)acc[qt][dt][r];
            }
    }
}

// ---------------- Kernel 2b: merge splits (r12 verbatim) ----------------
__global__ __launch_bounds__(256) void merge_kernel(
    const bf16_t* __restrict__ p1,
    const float* __restrict__ lbuf,
    bf16_t* __restrict__ p0)
{
    const size_t f8 = ((size_t)blockIdx.x * 256 + threadIdx.x) * 8;
    const int row = (int)(f8 >> 10);          // 0..4095
    const int col = (int)(f8 & 1023);
    const int b = row >> 11, t = row & 2047;
    const int h = col >> 6;
    const int li = (b * 16 + h) * 2048 + t;
    const float rinv = 1.0f / (lbuf[li] + lbuf[32 * 2048 + li]);
    bf16x8 a = *(const bf16x8*)(p0 + f8);
    bf16x8 c = *(const bf16x8*)(p1 + f8);
    bf16x8 o;
#pragma unroll
    for (int k = 0; k < 8; k++)
        o[k] = (bf16_t)(((float)a[k] + (float)c[k]) * rinv);
    *(bf16x8*)(p0 + f8) = o;
}

// ---------------- Kernel 3: output projection GEMM (BK=64, swizzled LDS) ----------------
__global__ __launch_bounds__(256, 2) void out_gemm_kernel(
    const bf16_t* __restrict__ attn,
    const bf16_t* __restrict__ wt,      // out_w^T bf16 [1024][1024]
    const float* __restrict__ out_b,
    float* __restrict__ out)
{
    __shared__ bf16_t L[2][2][128 * 64];

    const int tid = threadIdx.x;
    const int w = tid >> 6, ln = tid & 63;
    const int g = ln >> 4, qc = ln & 15;
    const int braw = blockIdx.x;
    const int bsw = (braw & 7) * 32 + (braw >> 3);   // 256 blocks
    const int n0 = (bsw & 7) * 128, m0 = (bsw >> 3) * 128;
    const int wm = (w >> 1) * 64, wn = (w & 1) * 64;
    const int srow = ln >> 3, sslot = ln & 7;
    const int scol = (sslot ^ srow) * 8;

    f32x4 acc[4][4];
    const f32x4 z = {0.f, 0.f, 0.f, 0.f};
#pragma unroll
    for (int i = 0; i < 4; i++)
#pragma unroll
        for (int j = 0; j < 4; j++) acc[i][j] = z;

    const bf16_t* Abase = attn + (size_t)(m0 + w * 32 + srow) * 1024 + scol;
    const bf16_t* Bbase = wt   + (size_t)(n0 + w * 32 + srow) * 1024 + scol;

#define OG_STAGE(buf, k0)                                                        \
    {                                                                            \
        _Pragma("unroll")                                                        \
        for (int i = 0; i < 4; i++) {                                            \
            gload_lds16(Abase + (size_t)i * 8 * 1024 + (k0), &L[buf][0][(w * 32 + i * 8) * 64]); \
            gload_lds16(Bbase + (size_t)i * 8 * 1024 + (k0), &L[buf][1][(w * 32 + i * 8) * 64]); \
        }                                                                        \
    }

    OG_STAGE(0, 0);
    __syncthreads();

    int cur = 0;
    const int swz = qc & 7;
    for (int ks = 0; ks < 16; ks++) {
        if (ks < 15) OG_STAGE(cur ^ 1, (ks + 1) * 64);
        bf16x8 af[2][4], bfv[2][4];
#pragma unroll
        for (int kk = 0; kk < 2; kk++) {
#pragma unroll
            for (int i = 0; i < 4; i++)
                af[kk][i]  = *(const bf16x8*)&L[cur][0][(wm + i * 16 + qc) * 64 + (((kk * 4 + g) ^ swz) * 8)];
#pragma unroll
            for (int j = 0; j < 4; j++)
                bfv[kk][j] = *(const bf16x8*)&L[cur][1][(wn + j * 16 + qc) * 64 + (((kk * 4 + g) ^ swz) * 8)];
        }
#pragma unroll
        for (int kk = 0; kk < 2; kk++)
#pragma unroll
            for (int i = 0; i < 4; i++)
#pragma unroll
                for (int j = 0; j < 4; j++)
                    acc[i][j] = __builtin_amdgcn_mfma_f32_16x16x32_bf16(af[kk][i], bfv[kk][j], acc[i][j], 0, 0, 0);
        __syncthreads();
        cur ^= 1;
    }
#undef OG_STAGE

#pragma unroll
    for (int i = 0; i < 4; i++) {
#pragma unroll
        for (int j = 0; j < 4; j++) {
            const int colg = n0 + wn + j * 16 + qc;
            const float bias = out_b[colg];
#pragma unroll
            for (int r = 0; r < 4; r++) {
                const int rowg = m0 + wm + i * 16 + g * 4 + r;
                out[(size_t)rowg * 1024 + colg] = acc[i][j][r] + bias;
            }
        }
    }
}

extern "C" void kernel_launch(void* const* d_in, const int* in_sizes, int n_in,
                              void* d_out, int out_size, void* d_ws, size_t ws_size,
                              hipStream_t stream) {
    const float* x     = (const float*)d_in[0];
    const float* q     = (const float*)d_in[1];
    const float* kv_w  = (const float*)d_in[2];
    const float* kv_b  = (const float*)d_in[3];
    const float* out_w = (const float*)d_in[4];
    const float* out_b = (const float*)d_in[5];
    float* out = (float*)d_out;

    bf16_t* xb     = (bf16_t*)d_ws;                          // 8 MB; reused as split-1 partials
    bf16_t* kv_wt  = xb + (size_t)4096 * 1024;               // 4 MB; reused as l partials
    bf16_t* out_wt = kv_wt + (size_t)2048 * 1024;            // 2 MB
    bf16_t* Kbuf   = out_wt + (size_t)1024 * 1024;           // 8 MB
    bf16_t* Vt     = Kbuf + (size_t)32 * 2048 * 64;          // 8 MB
    bf16_t* attnb  = Vt + (size_t)32 * 2048 * 64;            // 8 MB; split-0 partials, merged in place

    prep_kernel<<<dim3(1792), 256, 0, stream>>>(x, kv_w, out_w, xb, kv_wt, out_wt);
    kv_gemm_kernel<<<dim3(512), 256, 0, stream>>>(xb, kv_wt, kv_b, Kbuf, Vt);
    attn_kernel<<<dim3(1024), 256, 0, stream>>>(q, Kbuf, Vt, attnb, xb, (float*)kv_wt);
    merge_kernel<<<dim3(2048), 256, 0, stream>>>(xb, (const float*)kv_wt, attnb);
    out_gemm_kernel<<<dim3(256), 256, 0, stream>>>(attnb, out_wt, out_b, out);
}

// Round 19
// 107.318 us; speedup vs baseline: 1.2376x; 1.0616x over previous
//
#include <hip/hip_runtime.h>
#include <hip/hip_bf16.h>

typedef __bf16 bf16_t;
typedef __attribute__((ext_vector_type(8))) __bf16 bf16x8;
typedef __attribute__((ext_vector_type(4))) float f32x4;
typedef __attribute__((ext_vector_type(2))) unsigned int u32x2;
typedef unsigned int u32;
typedef unsigned short u16;

// B=2, T=2048, D=1024, H=16, HD=64

__device__ __forceinline__ u32 pack2(float a, float b) {
    u16 ua = __builtin_bit_cast(u16, (bf16_t)a);
    u16 ub = __builtin_bit_cast(u16, (bf16_t)b);
    return (u32)ua | ((u32)ub << 16);
}

__device__ __forceinline__ bf16x8 cvt8(float4 f0, float4 f1) {
    bf16x8 v;
    v[0]=(bf16_t)f0.x; v[1]=(bf16_t)f0.y; v[2]=(bf16_t)f0.z; v[3]=(bf16_t)f0.w;
    v[4]=(bf16_t)f1.x; v[5]=(bf16_t)f1.y; v[6]=(bf16_t)f1.z; v[7]=(bf16_t)f1.w;
    return v;
}

__device__ __forceinline__ float exp2_fast(float x) {
    float r;
    asm("v_exp_f32 %0, %1" : "=v"(r) : "v"(x));
    return r;
}

__device__ __forceinline__ void gload_lds16(const void* g, void* l) {
    __builtin_amdgcn_global_load_lds(
        (const __attribute__((address_space(1))) unsigned int*)g,
        (__attribute__((address_space(3))) unsigned int*)l, 16, 0, 0);
}

// ---------------- Kernel 0: prep (convert + transpose weights) ----------------
__global__ __launch_bounds__(256) void prep_kernel(
    const float* __restrict__ x,
    const float* __restrict__ kv_w,
    const float* __restrict__ out_w,
    bf16_t* __restrict__ xb,
    bf16_t* __restrict__ kv_wt,
    bf16_t* __restrict__ out_wt)
{
    __shared__ bf16_t T[64 * 72];
    const int blk = blockIdx.x;
    const int tid = threadIdx.x;

    if (blk < 1024) {
        const size_t base = (size_t)blk * 4096 + tid * 16;
        const float4* p = (const float4*)(x + base);
        float4 f0 = p[0], f1 = p[1], f2 = p[2], f3 = p[3];
        *(bf16x8*)(xb + base)     = cvt8(f0, f1);
        *(bf16x8*)(xb + base + 8) = cvt8(f2, f3);
        return;
    }

    const bool is_kv = (blk < 1536);
    const int t = is_kv ? (blk - 1024) : (blk - 1536);
    const int k0 = is_kv ? (t >> 5) * 64 : (t >> 4) * 64;
    const int n0 = is_kv ? (t & 31) * 64 : (t & 15) * 64;
    const int srcld = is_kv ? 2048 : 1024;
    const float* W = is_kv ? kv_w : out_w;
    bf16_t* Wt = is_kv ? kv_wt : out_wt;

    {
        const int r = tid >> 2, c4 = (tid & 3) * 16;
        const float4* p = (const float4*)(W + (size_t)(k0 + r) * srcld + n0 + c4);
        float4 f0 = p[0], f1 = p[1], f2 = p[2], f3 = p[3];
        *(bf16x8*)&T[r * 72 + c4]     = cvt8(f0, f1);
        *(bf16x8*)&T[r * 72 + c4 + 8] = cvt8(f2, f3);
    }
    __syncthreads();
    {
        const int n = tid >> 2, kc = (tid & 3) * 16;
        bf16x8 o0, o1;
#pragma unroll
        for (int kk = 0; kk < 8; kk++) o0[kk] = T[(kc + kk) * 72 + n];
#pragma unroll
        for (int kk = 0; kk < 8; kk++) o1[kk] = T[(kc + 8 + kk) * 72 + n];
        *(bf16x8*)(Wt + (size_t)(n0 + n) * 1024 + k0 + kc)     = o0;
        *(bf16x8*)(Wt + (size_t)(n0 + n) * 1024 + k0 + kc + 8) = o1;
    }
}

// ---------------- Kernel 1: KV projection GEMM (BK=64, swizzled LDS) ----------------
// xb[4096][1024] @ kv_wt^T -> K[32][2048][64], Vt[32][64][2048]
__global__ __launch_bounds__(256, 2) void kv_gemm_kernel(
    const bf16_t* __restrict__ xb,
    const bf16_t* __restrict__ wt,      // [2048][1024]
    const float* __restrict__ kv_b,
    bf16_t* __restrict__ Kbuf,
    bf16_t* __restrict__ Vt)
{
    __shared__ bf16_t L[2][2][128 * 64];   // [buf][A/B][row][64], 64 KB

    const int tid = threadIdx.x;
    const int w = tid >> 6, ln = tid & 63;
    const int g = ln >> 4, qc = ln & 15;
    const int braw = blockIdx.x;
    const int bsw = (braw & 7) * 64 + (braw >> 3);   // 512 blocks
    const int n0 = (bsw & 15) * 128, m0 = (bsw >> 4) * 128;
    const int wm = (w >> 1) * 64, wn = (w & 1) * 64;
    const int srow = ln >> 3, sslot = ln & 7;
    const int scol = (sslot ^ srow) * 8;             // inverse-swizzled source chunk

    f32x4 acc[4][4];
    const f32x4 z = {0.f, 0.f, 0.f, 0.f};
#pragma unroll
    for (int i = 0; i < 4; i++)
#pragma unroll
        for (int j = 0; j < 4; j++) acc[i][j] = z;

    const bf16_t* Abase = xb + (size_t)(m0 + w * 32 + srow) * 1024 + scol;
    const bf16_t* Bbase = wt + (size_t)(n0 + w * 32 + srow) * 1024 + scol;

#define KV_STAGE(buf, k0)                                                        \
    {                                                                            \
        _Pragma("unroll")                                                        \
        for (int i = 0; i < 4; i++) {                                            \
            gload_lds16(Abase + (size_t)i * 8 * 1024 + (k0), &L[buf][0][(w * 32 + i * 8) * 64]); \
            gload_lds16(Bbase + (size_t)i * 8 * 1024 + (k0), &L[buf][1][(w * 32 + i * 8) * 64]); \
        }                                                                        \
    }

    KV_STAGE(0, 0);
    __syncthreads();

    int cur = 0;
    const int swz = qc & 7;
    for (int ks = 0; ks < 16; ks++) {
        if (ks < 15) KV_STAGE(cur ^ 1, (ks + 1) * 64);
        bf16x8 af[2][4], bfv[2][4];
#pragma unroll
        for (int kk = 0; kk < 2; kk++) {
#pragma unroll
            for (int i = 0; i < 4; i++)
                af[kk][i]  = *(const bf16x8*)&L[cur][0][(wm + i * 16 + qc) * 64 + (((kk * 4 + g) ^ swz) * 8)];
#pragma unroll
            for (int j = 0; j < 4; j++)
                bfv[kk][j] = *(const bf16x8*)&L[cur][1][(wn + j * 16 + qc) * 64 + (((kk * 4 + g) ^ swz) * 8)];
        }
#pragma unroll
        for (int kk = 0; kk < 2; kk++)
#pragma unroll
            for (int i = 0; i < 4; i++)
#pragma unroll
                for (int j = 0; j < 4; j++)
                    acc[i][j] = __builtin_amdgcn_mfma_f32_16x16x32_bf16(af[kk][i], bfv[kk][j], acc[i][j], 0, 0, 0);
        __syncthreads();
        cur ^= 1;
    }
#undef KV_STAGE

    if (n0 < 1024) {
        // K half: d-contiguous stores
#pragma unroll
        for (int i = 0; i < 4; i++) {
#pragma unroll
            for (int j = 0; j < 4; j++) {
                const int colg = n0 + wn + j * 16 + qc;
                const float bias = kv_b[colg];
                const int h = colg >> 6, d = colg & 63;
#pragma unroll
                for (int r = 0; r < 4; r++) {
                    const int rowg = m0 + wm + i * 16 + g * 4 + r;
                    const int b = rowg >> 11, t = rowg & 2047;
                    Kbuf[(((size_t)(b * 16 + h) * 2048 + t) << 6) + d] = (bf16_t)(acc[i][j][r] + bias);
                }
            }
        }
    } else {
        // V half: transpose via LDS (pad 134), then coalesced 16B stores
        bf16_t* T = (bf16_t*)L;
#pragma unroll
        for (int i = 0; i < 4; i++) {
#pragma unroll
            for (int j = 0; j < 4; j++) {
                const int nloc = wn + j * 16 + qc;
                const float bias = kv_b[n0 + nloc];
                const int mloc = wm + i * 16 + g * 4;
                *(u32*)&T[nloc * 134 + mloc]     = pack2(acc[i][j][0] + bias, acc[i][j][1] + bias);
                *(u32*)&T[nloc * 134 + mloc + 2] = pack2(acc[i][j][2] + bias, acc[i][j][3] + bias);
            }
        }
        __syncthreads();
        const int n = tid >> 1, mh = (tid & 1) * 64;
        const int d = n0 - 1024 + n;
        const int b = m0 >> 11;
        const int t0 = (m0 & 2047) + mh;
        bf16_t* dst = Vt + (((size_t)(b * 16 + (d >> 6)) * 64 + (d & 63)) << 11) + t0;
#pragma unroll
        for (int k = 0; k < 8; k++)
            *(bf16x8*)(dst + k * 8) = *(const bf16x8*)&T[n * 134 + mh + k * 8];
    }
}

// ---------------- Kernel 2: fused attention (round-11 verbatim, best known) ----------------
__global__ __launch_bounds__(256) void attn_kernel(
    const float* __restrict__ q,
    const bf16_t* __restrict__ Kbuf,
    const bf16_t* __restrict__ Vt,
    bf16_t* __restrict__ attn)
{
    __shared__ bf16_t Klds[2][64 * 64];
    __shared__ bf16_t Vlds[2][64 * 64];
    __shared__ bf16_t Plds[4][2][16 * 72];

    const int tid = threadIdx.x;
    const int wv = tid >> 6;
    const int ln = tid & 63;
    const int g = ln >> 4, qc = ln & 15;

    const int braw = blockIdx.x;
    const int bsw = (braw & 7) * 64 + (braw >> 3);
    const int bh = bsw >> 4;
    const int qb = bsw & 15;
    const int b = bh >> 4, h = bh & 15;
    const int q0 = qb * 128 + wv * 32;

    const float qscale = 0.125f * 1.44269504088896f;
    bf16x8 qf[2][2];
#pragma unroll
    for (int qt = 0; qt < 2; qt++) {
        const float* qp = q + ((size_t)(b * 2048 + q0 + qt * 16 + qc) * 1024) + h * 64 + g * 8;
#pragma unroll
        for (int c = 0; c < 2; c++) {
            float4 f0 = *(const float4*)(qp + c * 32);
            float4 f1 = *(const float4*)(qp + c * 32 + 4);
            f0.x*=qscale; f0.y*=qscale; f0.z*=qscale; f0.w*=qscale;
            f1.x*=qscale; f1.y*=qscale; f1.z*=qscale; f1.w*=qscale;
            qf[qt][c] = cvt8(f0, f1);
        }
    }

    const bf16_t* Kb = Kbuf + (size_t)bh * (2048 * 64);
    const bf16_t* Vb = Vt + (size_t)bh * (64 * 2048);

    float l_part[2] = {0.0f, 0.0f};
    f32x4 acc[2][4];
    const f32x4 z = {0.f, 0.f, 0.f, 0.f};
#pragma unroll
    for (int qt = 0; qt < 2; qt++)
#pragma unroll
        for (int dt = 0; dt < 4; dt++) acc[qt][dt] = z;

    const int srow = ln >> 3;
    const int sc16 = ln & 7;

#pragma unroll
    for (int i = 0; i < 2; i++) {
        const int row = wv * 16 + i * 8 + srow;
        const int slot = sc16 ^ (row & 7);
        gload_lds16(Kb + (size_t)row * 64 + slot * 8,       &Klds[0][(wv * 16 + i * 8) * 64]);
        gload_lds16(Vb + (size_t)row * 2048 + 0 + slot * 8, &Vlds[0][(wv * 16 + i * 8) * 64]);
    }
    __syncthreads();

    int cur = 0;
    for (int t = 0; t < 32; ++t) {
        const int kv0 = t * 64;
        if (t + 1 < 32) {
            const int kvn = kv0 + 64;
#pragma unroll
            for (int i = 0; i < 2; i++) {
                const int row = wv * 16 + i * 8 + srow;
                const int slot = sc16 ^ (row & 7);
                gload_lds16(Kb + (size_t)(kvn + row) * 64 + slot * 8, &Klds[cur ^ 1][(wv * 16 + i * 8) * 64]);
                gload_lds16(Vb + (size_t)row * 2048 + kvn + slot * 8, &Vlds[cur ^ 1][(wv * 16 + i * 8) * 64]);
            }
        }

        const bf16_t* Kl = Klds[cur];
        const bf16_t* Vl = Vlds[cur];

        // ---- S^T = K · Q^T  (already in exp2 domain; no further scaling)
        f32x4 st[4][2];
#pragma unroll
        for (int kt = 0; kt < 4; kt++) {
            bf16x8 k0 = *(const bf16x8*)&Kl[(kt * 16 + qc) * 64 + ((g       ^ (qc & 7)) * 8)];
            bf16x8 k1 = *(const bf16x8*)&Kl[(kt * 16 + qc) * 64 + (((4 + g) ^ (qc & 7)) * 8)];
#pragma unroll
            for (int qt = 0; qt < 2; qt++) {
                f32x4 s = __builtin_amdgcn_mfma_f32_16x16x32_bf16(k0, qf[qt][0], z, 0, 0, 0);
                st[kt][qt] = __builtin_amdgcn_mfma_f32_16x16x32_bf16(k1, qf[qt][1], s, 0, 0, 0);
            }
        }

        bf16x8 vf[4][2];
#pragma unroll
        for (int dt = 0; dt < 4; dt++)
#pragma unroll
            for (int ks = 0; ks < 2; ks++)
                vf[dt][ks] = *(const bf16x8*)&Vl[(dt * 16 + qc) * 64 + (((ks * 4 + g) ^ (qc & 7)) * 8)];

        // ---- unnormalized softmax: p = exp2(s) directly
#pragma unroll
        for (int qt = 0; qt < 2; qt++) {
            float p[16];
            float s0 = 0.f, s1 = 0.f;
#pragma unroll
            for (int kt = 0; kt < 4; kt++)
#pragma unroll
                for (int r = 0; r < 4; r++) {
                    float pv = exp2_fast(st[kt][qt][r]);
                    p[kt * 4 + r] = pv;
                    if (r & 1) s1 += pv; else s0 += pv;
                }
            l_part[qt] += s0 + s1;

            bf16_t* Pq = &Plds[wv][qt][0];
#pragma unroll
            for (int kt = 0; kt < 4; kt++) {
                u32x2 wpk;
                wpk[0] = pack2(p[kt * 4 + 0], p[kt * 4 + 1]);
                wpk[1] = pack2(p[kt * 4 + 2], p[kt * 4 + 3]);
                *(u32x2*)&Pq[qc * 72 + kt * 16 + g * 4] = wpk;
            }
        }

        // ---- P·V
#pragma unroll
        for (int qt = 0; qt < 2; qt++) {
            bf16x8 pf0 = *(const bf16x8*)&Plds[wv][qt][qc * 72 + g * 8];
            bf16x8 pf1 = *(const bf16x8*)&Plds[wv][qt][qc * 72 + 32 + g * 8];
#pragma unroll
            for (int dt = 0; dt < 4; dt++) {
                acc[qt][dt] = __builtin_amdgcn_mfma_f32_16x16x32_bf16(pf0, vf[dt][0], acc[qt][dt], 0, 0, 0);
                acc[qt][dt] = __builtin_amdgcn_mfma_f32_16x16x32_bf16(pf1, vf[dt][1], acc[qt][dt], 0, 0, 0);
            }
        }

        __syncthreads();
        cur ^= 1;
    }

    // ---- normalize & store
#pragma unroll
    for (int qt = 0; qt < 2; qt++) {
        float lsum = l_part[qt];
        lsum += __shfl_xor(lsum, 16);
        lsum += __shfl_xor(lsum, 32);
        float li[4];
#pragma unroll
        for (int r = 0; r < 4; r++) li[r] = 1.0f / __shfl(lsum, g * 4 + r);
#pragma unroll
        for (int dt = 0; dt < 4; dt++)
#pragma unroll
            for (int r = 0; r < 4; r++) {
                const float o = acc[qt][dt][r] * li[r];
                const int trow = q0 + qt * 16 + g * 4 + r;
                attn[((size_t)(b * 2048 + trow)) * 1024 + h * 64 + dt * 16 + qc] = (bf16_t)o;
            }
    }
}

// ---------------- Kernel 3: output projection GEMM (BK=64, swizzled LDS) ----------------
__global__ __launch_bounds__(256, 2) void out_gemm_kernel(
    const bf16_t* __restrict__ attn,
    const bf16_t* __restrict__ wt,      // out_w^T bf16 [1024][1024]
    const float* __restrict__ out_b,
    float* __restrict__ out)
{
    __shared__ bf16_t L[2][2][128 * 64];

    const int tid = threadIdx.x;
    const int w = tid >> 6, ln = tid & 63;
    const int g = ln >> 4, qc = ln & 15;
    const int braw = blockIdx.x;
    const int bsw = (braw & 7) * 32 + (braw >> 3);   // 256 blocks
    const int n0 = (bsw & 7) * 128, m0 = (bsw >> 3) * 128;
    const int wm = (w >> 1) * 64, wn = (w & 1) * 64;
    const int srow = ln >> 3, sslot = ln & 7;
    const int scol = (sslot ^ srow) * 8;

    f32x4 acc[4][4];
    const f32x4 z = {0.f, 0.f, 0.f, 0.f};
#pragma unroll
    for (int i = 0; i < 4; i++)
#pragma unroll
        for (int j = 0; j < 4; j++) acc[i][j] = z;

    const bf16_t* Abase = attn + (size_t)(m0 + w * 32 + srow) * 1024 + scol;
    const bf16_t* Bbase = wt   + (size_t)(n0 + w * 32 + srow) * 1024 + scol;

#define OG_STAGE(buf, k0)                                                        \
    {                                                                            \
        _Pragma("unroll")                                                        \
        for (int i = 0; i < 4; i++) {                                            \
            gload_lds16(Abase + (size_t)i * 8 * 1024 + (k0), &L[buf][0][(w * 32 + i * 8) * 64]); \
            gload_lds16(Bbase + (size_t)i * 8 * 1024 + (k0), &L[buf][1][(w * 32 + i * 8) * 64]); \
        }                                                                        \
    }

    OG_STAGE(0, 0);
    __syncthreads();

    int cur = 0;
    const int swz = qc & 7;
    for (int ks = 0; ks < 16; ks++) {
        if (ks < 15) OG_STAGE(cur ^ 1, (ks + 1) * 64);
        bf16x8 af[2][4], bfv[2][4];
#pragma unroll
        for (int kk = 0; kk < 2; kk++) {
#pragma unroll
            for (int i = 0; i < 4; i++)
                af[kk][i]  = *(const bf16x8*)&L[cur][0][(wm + i * 16 + qc) * 64 + (((kk * 4 + g) ^ swz) * 8)];
#pragma unroll
            for (int j = 0; j < 4; j++)
                bfv[kk][j] = *(const bf16x8*)&L[cur][1][(wn + j * 16 + qc) * 64 + (((kk * 4 + g) ^ swz) * 8)];
        }
#pragma unroll
        for (int kk = 0; kk < 2; kk++)
#pragma unroll
            for (int i = 0; i < 4; i++)
#pragma unroll
                for (int j = 0; j < 4; j++)
                    acc[i][j] = __builtin_amdgcn_mfma_f32_16x16x32_bf16(af[kk][i], bfv[kk][j], acc[i][j], 0, 0, 0);
        __syncthreads();
        cur ^= 1;
    }
#undef OG_STAGE

#pragma unroll
    for (int i = 0; i < 4; i++) {
#pragma unroll
        for (int j = 0; j < 4; j++) {
            const int colg = n0 + wn + j * 16 + qc;
            const float bias = out_b[colg];
#pragma unroll
            for (int r = 0; r < 4; r++) {
                const int rowg = m0 + wm + i * 16 + g * 4 + r;
                out[(size_t)rowg * 1024 + colg] = acc[i][j][r] + bias;
            }
        }
    }
}

extern "C" void kernel_launch(void* const* d_in, const int* in_sizes, int n_in,
                              void* d_out, int out_size, void* d_ws, size_t ws_size,
                              hipStream_t stream) {
    const float* x     = (const float*)d_in[0];
    const float* q     = (const float*)d_in[1];
    const float* kv_w  = (const float*)d_in[2];
    const float* kv_b  = (const float*)d_in[3];
    const float* out_w = (const float*)d_in[4];
    const float* out_b = (const float*)d_in[5];
    float* out = (float*)d_out;

    bf16_t* xb     = (bf16_t*)d_ws;
    bf16_t* kv_wt  = xb + (size_t)4096 * 1024;
    bf16_t* out_wt = kv_wt + (size_t)2048 * 1024;
    bf16_t* Kbuf   = out_wt + (size_t)1024 * 1024;
    bf16_t* Vt     = Kbuf + (size_t)32 * 2048 * 64;
    bf16_t* attnb  = Vt + (size_t)32 * 2048 * 64;

    prep_kernel<<<dim3(1792), 256, 0, stream>>>(x, kv_w, out_w, xb, kv_wt, out_wt);
    kv_gemm_kernel<<<dim3(512), 256, 0, stream>>>(xb, kv_wt, kv_b, Kbuf, Vt);
    attn_kernel<<<dim3(512), 256, 0, stream>>>(q, Kbuf, Vt, attnb);
    out_gemm_kernel<<<dim3(256), 256, 0, stream>>>(attnb, out_wt, out_b, out);
}